// Round 10
// baseline (488.666 us; speedup 1.0000x reference)
//
#include <hip/hip_runtime.h>
#include <cstdint>
#include <cstddef>

// DynamicHierarchicalAttention — MFMA pipeline.
// R9: attn1 split-K x4 (KC=4): k-loop partitioned (no extra DS work), grid
// 1024 = 4 blocks/CU = 16 waves/CU — fixes the latency-bound 8-wave regime
// R8 created (nothing saturated: MFMA 23%, VALU 39%, DS ~14us of 49us).
// O partials stored f16 (|O|~14, rel 4.9e-4 -> ~3e-6 on outputs) to keep
// HBM + ws in budget; l partials stay f32.  S^T trick (R8), qkv f16 (R5),
// GEMMs split-f16 (fp32-grade).

#define TB 2
#define TT 2048
#define TD 512
#define TH 8
#define THD 64
#define KC 4   // k-chunks in attn1

#define MI_M1 0
#define MI_M2 1
#define MI_NTOK 2
#define MI_OFF_CW 3
#define MI_OFF_BW 4
#define MI_OFF_GW 5
#define MI_MCHAR 6
#define MI_MBLOCK 7
#define MI_MGLOB 8
#define MI_SEQC 9
#define MI_SEQB 10
#define MI_SEQG 11

typedef _Float16 half8 __attribute__((ext_vector_type(8)));
typedef _Float16 half4 __attribute__((ext_vector_type(4)));
typedef _Float16 half2_t __attribute__((ext_vector_type(2)));
typedef float floatx4 __attribute__((ext_vector_type(4)));

__device__ __forceinline__ floatx4 mfma16(half8 a, half8 b, floatx4 c) {
  return __builtin_amdgcn_mfma_f32_16x16x32_f16(a, b, c, 0, 0, 0);
}
__device__ __forceinline__ floatx4 mfma16k16(half4 a, half4 b, floatx4 c) {
  return __builtin_amdgcn_mfma_f32_16x16x16f16(a, b, c, 0, 0, 0);
}

__device__ __forceinline__ double fracd(double x) { return x - floor(x); }

// ---------------------------------------------------------------------------
// parallel boundary scan for one phase: n elements, increment c.
// ---------------------------------------------------------------------------
__device__ int scan_phase(int n, double c, int* __restrict__ ids,
                          int* __restrict__ startg, float* __restrict__ cntg,
                          int* __restrict__ wsum, int t)
{
  int loc[8];
  const int base = t * 8;
#pragma unroll
  for (int j = 0; j < 8; ++j) {
    const int i = base + j;
    int f = 0;
    if (i < n) {
      const int pidx = (i == 0) ? n : i;   // roll: prev of elem 0 is elem n-1
      f = (fracd((double)(i + 1) * c) < fracd((double)pidx * c)) ? 1 : 0;
    }
    loc[j] = f + ((j > 0) ? loc[j - 1] : 0);
  }
  wsum[t] = loc[7];
  __syncthreads();
  for (int off = 1; off < 256; off <<= 1) {
    int u = 0;
    if (t >= off) u = wsum[t - off];
    __syncthreads();
    wsum[t] += u;
    __syncthreads();
  }
  const int excl = wsum[t] - loc[7];
  const int m = wsum[255];
#pragma unroll
  for (int j = 0; j < 8; ++j) {
    const int i = base + j;
    if (i < n) {
      const int id = excl + loc[j];
      ids[i] = id;
      const int f = loc[j] - ((j > 0) ? loc[j - 1] : 0);
      if (f) startg[id - 1] = i;
    }
  }
  __syncthreads();
  for (int j = t; j < m; j += 256)
    cntg[j] = (float)((((j + 1) < m) ? startg[j + 1] : n) - startg[j]);
  __syncthreads();
  return m;
}

// ---------------------------------------------------------------------------
__global__ __launch_bounds__(256)
void meta_kernel(const float* __restrict__ mw, const float* __restrict__ mb,
                 const float* __restrict__ gw, const float* __restrict__ gb,
                 int* __restrict__ mi,
                 int* __restrict__ start1, float* __restrict__ cnt1,
                 int* __restrict__ start2, float* __restrict__ cnt2,
                 int* __restrict__ gmap)
{
  __shared__ int ids1[TT];
  __shared__ int ids2[TT];
  __shared__ int wsum[256];
  __shared__ double dsh[256];
  const int t = threadIdx.x;

  double s1 = 0.0, s2 = 0.0;
  for (int i = t; i < TD; i += 256) { s1 += (double)mw[i]; s2 += (double)gw[i]; }
  dsh[t] = s1; __syncthreads();
  for (int off = 128; off > 0; off >>= 1) {
    if (t < off) dsh[t] += dsh[t + off];
    __syncthreads();
  }
  const double c1 = dsh[0] + (double)mb[0];
  __syncthreads();
  dsh[t] = s2; __syncthreads();
  for (int off = 128; off > 0; off >>= 1) {
    if (t < off) dsh[t] += dsh[t + off];
    __syncthreads();
  }
  const double c2 = dsh[0] + (double)gb[0];
  __syncthreads();

  const int m1 = scan_phase(TT, c1, ids1, start1, cnt1, wsum, t);
  const int m2 = scan_phase(m1, c2, ids2, start2, cnt2, wsum, t);

  int i0 = TT;
  if (m1 >= 1 && m2 >= 1) i0 = start1[start2[0]];
  const int ntok = TT - i0;

  if (t == 0) {
    mi[MI_M1] = m1; mi[MI_M2] = m2; mi[MI_NTOK] = ntok;
    const int offcw = TB * ntok * TD;
    mi[MI_OFF_CW] = offcw;
    mi[MI_OFF_BW] = offcw + TB * TT * TT;
    mi[MI_OFF_GW] = offcw + TB * TT * TT + TB * m1 * m1;
    mi[MI_MCHAR] = TB * TT;
    mi[MI_MBLOCK] = TB * m1;
    mi[MI_MGLOB] = TB * m2;
    mi[MI_SEQC] = TT;
    mi[MI_SEQB] = m1;
    mi[MI_SEQG] = m2;
  }
  for (int i = i0 + t; i < TT; i += 256)
    gmap[i - i0] = ids2[ids1[i] - 1] - 1;
}

// ---------------------------------------------------------------------------
// GEMM 128m x 64n tile: C[M,N] = A[M,512] @ W[N,512]^T + bias, split-f16.
// ---------------------------------------------------------------------------
template <typename OutT>
__global__ __launch_bounds__(256)
void gemm_mfma(const float* __restrict__ A, const float* __restrict__ W,
               const float* __restrict__ bias, OutT* __restrict__ C,
               const int* __restrict__ mi, int m_slot, int N)
{
  const int M = mi[m_slot];
  const int bm = blockIdx.y * 128;
  if (bm >= M) return;
  const int bn = blockIdx.x * 64;
  __shared__ _Float16 Ah[128][40];
  __shared__ _Float16 Al[128][40];
  __shared__ _Float16 Wh[64][40];
  __shared__ _Float16 Wl[64][40];

  const int t = threadIdx.x;
  const int wv = t >> 6;
  const int lane = t & 63;
  const int l15 = lane & 15;
  const int quad = lane >> 4;
  const int srowA = t >> 1;
  const int ssegA = (t & 1) * 16;
  const int srowW = t >> 2;
  const int ssegW = (t & 3) * 8;

  floatx4 acc[2][4];
#pragma unroll
  for (int i = 0; i < 2; ++i)
#pragma unroll
    for (int j = 0; j < 4; ++j) acc[i][j] = (floatx4){0.f, 0.f, 0.f, 0.f};

  for (int kk = 0; kk < TD; kk += 32) {
    __syncthreads();
    {
      const int ar = bm + srowA;
#pragma unroll
      for (int u = 0; u < 4; ++u) {
        float4 av = make_float4(0.f, 0.f, 0.f, 0.f);
        if (ar < M) av = *(const float4*)&A[(size_t)ar * TD + kk + ssegA + u * 4];
        const float aa[4] = {av.x, av.y, av.z, av.w};
        half4 hi, lo;
#pragma unroll
        for (int e = 0; e < 4; ++e) {
          const _Float16 h = (_Float16)aa[e];
          hi[e] = h; lo[e] = (_Float16)(aa[e] - (float)h);
        }
        *(half4*)&Ah[srowA][ssegA + u * 4] = hi;
        *(half4*)&Al[srowA][ssegA + u * 4] = lo;
      }
#pragma unroll
      for (int u = 0; u < 2; ++u) {
        const float4 wvv = *(const float4*)&W[(size_t)(bn + srowW) * TD + kk + ssegW + u * 4];
        const float ww[4] = {wvv.x, wvv.y, wvv.z, wvv.w};
        half4 hi, lo;
#pragma unroll
        for (int e = 0; e < 4; ++e) {
          const _Float16 h = (_Float16)ww[e];
          hi[e] = h; lo[e] = (_Float16)(ww[e] - (float)h);
        }
        *(half4*)&Wh[srowW][ssegW + u * 4] = hi;
        *(half4*)&Wl[srowW][ssegW + u * 4] = lo;
      }
    }
    __syncthreads();
    half8 ah[2], al[2];
#pragma unroll
    for (int mp = 0; mp < 2; ++mp) {
      ah[mp] = *(const half8*)&Ah[wv * 32 + mp * 16 + l15][quad * 8];
      al[mp] = *(const half8*)&Al[wv * 32 + mp * 16 + l15][quad * 8];
    }
#pragma unroll
    for (int np = 0; np < 4; ++np) {
      const half8 bh = *(const half8*)&Wh[np * 16 + l15][quad * 8];
      const half8 bl = *(const half8*)&Wl[np * 16 + l15][quad * 8];
#pragma unroll
      for (int mp = 0; mp < 2; ++mp) {
        acc[mp][np] = mfma16(al[mp], bh, acc[mp][np]);
        acc[mp][np] = mfma16(ah[mp], bl, acc[mp][np]);
        acc[mp][np] = mfma16(ah[mp], bh, acc[mp][np]);
      }
    }
  }
  float bv[4];
#pragma unroll
  for (int np = 0; np < 4; ++np) bv[np] = bias[bn + np * 16 + l15];
#pragma unroll
  for (int mp = 0; mp < 2; ++mp) {
#pragma unroll
    for (int r = 0; r < 4; ++r) {
      const int row = bm + wv * 32 + mp * 16 + quad * 4 + r;
      if (row < M) {
        OutT* cp = &C[(size_t)row * N + bn];
#pragma unroll
        for (int np = 0; np < 4; ++np)
          cp[np * 16 + l15] = (OutT)(acc[mp][np][r] + bv[np]);
      }
    }
  }
}

// ---------------------------------------------------------------------------
// Proj GEMM with fused combine: A-row = (sum_z O_z) * 1/(sum_z l_z).
// O partials f16 [KC][M*512]; l partials f32 [KC][32768].
// ---------------------------------------------------------------------------
__global__ __launch_bounds__(256)
void gemm_norm_mfma(const _Float16* __restrict__ Ob, const float* __restrict__ lb,
                    const float* __restrict__ W, const float* __restrict__ bias,
                    float* __restrict__ C, const int* __restrict__ mi,
                    int m_slot, int seq_slot)
{
  const int M = mi[m_slot];
  const int bm = blockIdx.y * 128;
  if (bm >= M) return;
  const int seq = mi[seq_slot];
  const int bn = blockIdx.x * 64;
  __shared__ _Float16 Ah[128][40];
  __shared__ _Float16 Al[128][40];
  __shared__ _Float16 Wh[64][40];
  __shared__ _Float16 Wl[64][40];

  const int t = threadIdx.x;
  const int wv = t >> 6;
  const int lane = t & 63;
  const int l15 = lane & 15;
  const int quad = lane >> 4;
  const int srowA = t >> 1;
  const int ssegA = (t & 1) * 16;
  const int srowW = t >> 2;
  const int ssegW = (t & 3) * 8;

  const int ar = bm + srowA;
  const int ab = (ar >= seq) ? 1 : 0;
  const int aq = ar - ab * seq;

  floatx4 acc[2][4];
#pragma unroll
  for (int i = 0; i < 2; ++i)
#pragma unroll
    for (int j = 0; j < 4; ++j) acc[i][j] = (floatx4){0.f, 0.f, 0.f, 0.f};

  for (int kk = 0; kk < TD; kk += 32) {
    __syncthreads();
    {
      float linv = 0.f;
      if (ar < M) {
        const int h = kk >> 6;
        const size_t lidx = ((size_t)(ab * TH + h)) * 2048 + aq;
        float lt = 0.f;
#pragma unroll
        for (int z = 0; z < KC; ++z) lt += lb[(size_t)z * 32768 + lidx];
        linv = 1.f / lt;
      }
#pragma unroll
      for (int u = 0; u < 4; ++u) {
        float aa[4] = {0.f, 0.f, 0.f, 0.f};
        if (ar < M) {
          const size_t off = (size_t)ar * TD + kk + ssegA + u * 4;
#pragma unroll
          for (int z = 0; z < KC; ++z) {
            const half4 hv = *(const half4*)&Ob[(size_t)z * 2097152 + off];
#pragma unroll
            for (int e = 0; e < 4; ++e) aa[e] += (float)hv[e];
          }
#pragma unroll
          for (int e = 0; e < 4; ++e) aa[e] *= linv;
        }
        half4 hi, lo;
#pragma unroll
        for (int e = 0; e < 4; ++e) {
          const _Float16 h = (_Float16)aa[e];
          hi[e] = h; lo[e] = (_Float16)(aa[e] - (float)h);
        }
        *(half4*)&Ah[srowA][ssegA + u * 4] = hi;
        *(half4*)&Al[srowA][ssegA + u * 4] = lo;
      }
#pragma unroll
      for (int u = 0; u < 2; ++u) {
        const float4 wvv = *(const float4*)&W[(size_t)(bn + srowW) * TD + kk + ssegW + u * 4];
        const float ww[4] = {wvv.x, wvv.y, wvv.z, wvv.w};
        half4 hi, lo;
#pragma unroll
        for (int e = 0; e < 4; ++e) {
          const _Float16 h = (_Float16)ww[e];
          hi[e] = h; lo[e] = (_Float16)(ww[e] - (float)h);
        }
        *(half4*)&Wh[srowW][ssegW + u * 4] = hi;
        *(half4*)&Wl[srowW][ssegW + u * 4] = lo;
      }
    }
    __syncthreads();
    half8 ah[2], al[2];
#pragma unroll
    for (int mp = 0; mp < 2; ++mp) {
      ah[mp] = *(const half8*)&Ah[wv * 32 + mp * 16 + l15][quad * 8];
      al[mp] = *(const half8*)&Al[wv * 32 + mp * 16 + l15][quad * 8];
    }
#pragma unroll
    for (int np = 0; np < 4; ++np) {
      const half8 bh = *(const half8*)&Wh[np * 16 + l15][quad * 8];
      const half8 bl = *(const half8*)&Wl[np * 16 + l15][quad * 8];
#pragma unroll
      for (int mp = 0; mp < 2; ++mp) {
        acc[mp][np] = mfma16(al[mp], bh, acc[mp][np]);
        acc[mp][np] = mfma16(ah[mp], bl, acc[mp][np]);
        acc[mp][np] = mfma16(ah[mp], bh, acc[mp][np]);
      }
    }
  }
  float bv[4];
#pragma unroll
  for (int np = 0; np < 4; ++np) bv[np] = bias[bn + np * 16 + l15];
#pragma unroll
  for (int mp = 0; mp < 2; ++mp) {
#pragma unroll
    for (int r = 0; r < 4; ++r) {
      const int row = bm + wv * 32 + mp * 16 + quad * 4 + r;
      if (row < M) {
        float* cp = &C[(size_t)row * 512 + bn];
#pragma unroll
        for (int np = 0; np < 4; ++np)
          cp[np * 16 + l15] = acc[mp][np][r] + bv[np];
      }
    }
  }
}

// ---------------------------------------------------------------------------
// attn pass1, split-K x4 (z = chunk), S^T-trick.  q-tile 128, 4 waves x 32 q.
// Partials: O_z f16 (unnormalized), l_z f32.
// ---------------------------------------------------------------------------
__global__ __launch_bounds__(256)
void attn1_mfma(const _Float16* __restrict__ qkv,
                float* __restrict__ lbase, _Float16* __restrict__ Obase,
                const int* __restrict__ mi, int seq_slot)
{
  const int seq = mi[seq_slot];
  const int q0 = blockIdx.x * 128;
  if (q0 >= seq) return;
  const int b = blockIdx.y >> 3, h = blockIdx.y & 7;
  const int z = blockIdx.z;
  float* lP = lbase + (size_t)z * 32768;
  _Float16* oP = Obase + (size_t)z * 2097152;
  const int t = threadIdx.x;
  const int wv = t >> 6;
  const int lane = t & 63;
  const int l15 = lane & 15;
  const int quad = lane >> 4;

  __shared__ __align__(16) char smem_raw[18432];
  _Float16 (*Kf)[72] = (_Float16 (*)[72])smem_raw;              // 64x72 f16
  _Float16 (*Vt)[72] = (_Float16 (*)[72])(smem_raw + 9216);     // 64x72 f16
  float    (*Ot)[68] = (float (*)[68])smem_raw;                 // epilogue reuse

  // Q B-fragments: lane n=q=l15 of this mp-tile, k(d)=c*32+quad*8+j
  half8 qB[2][2];
#pragma unroll
  for (int mp = 0; mp < 2; ++mp) {
    const int qrow = q0 + wv * 32 + mp * 16 + l15;
#pragma unroll
    for (int c = 0; c < 2; ++c) {
      half8 v = {};
      if (qrow < seq)
        v = *(const half8*)&qkv[((size_t)(b * seq + qrow)) * 1536 + h * 64 + c * 32 + quad * 8];
      qB[mp][c] = v;
    }
  }
  half4 onesA;
#pragma unroll
  for (int j = 0; j < 4; ++j) onesA[j] = (_Float16)1.0f;

  floatx4 oacc[2][4];   // [mp][dblk] — O^T at (d=dblk*16+quad*4+r, q=l15)
#pragma unroll
  for (int i = 0; i < 2; ++i)
#pragma unroll
    for (int j = 0; j < 4; ++j) oacc[i][j] = (floatx4){0.f, 0.f, 0.f, 0.f};
  floatx4 lacc[2] = {(floatx4){0.f, 0.f, 0.f, 0.f}, (floatx4){0.f, 0.f, 0.f, 0.f}};

  const int nkt = (seq + 63) >> 6;
  const int nkc = (nkt + KC - 1) / KC;
  const int kt_beg = z * nkc;
  const int kt_end = min(kt_beg + nkc, nkt);

  for (int kt = kt_beg; kt < kt_end; ++kt) {
    const int k0 = kt * 64;
    __syncthreads();
    { // stage K [64][64]: thread row t>>2, 16 d at seg
      const int row = t >> 2;
      const int seg = (t & 3) * 16;
      const int kg = k0 + row;
      half8 v0 = {}, v1 = {};
      if (kg < seq) {
        const _Float16* base = &qkv[((size_t)(b * seq + kg)) * 1536 + 512 + h * 64 + seg];
        v0 = *(const half8*)base;
        v1 = *(const half8*)(base + 8);
      }
      *(half8*)&Kf[row][seg] = v0;
      *(half8*)&Kf[row][seg + 8] = v1;
    }
    { // stage V transposed: pair-packed b32 stores
      const int tp = lane & 31;
      const int dsel = lane >> 5;
      const int dbase = wv * 16 + dsel * 8;
      const int kg0 = k0 + tp * 2;
      half8 vA = {}, vB = {};
      if (kg0 < seq)
        vA = *(const half8*)&qkv[((size_t)(b * seq + kg0)) * 1536 + 1024 + h * 64 + dbase];
      if (kg0 + 1 < seq)
        vB = *(const half8*)&qkv[((size_t)(b * seq + kg0 + 1)) * 1536 + 1024 + h * 64 + dbase];
#pragma unroll
      for (int j = 0; j < 8; ++j) {
        half2_t pk; pk[0] = vA[j]; pk[1] = vB[j];
        *(half2_t*)&Vt[dbase + j][tp * 2] = pk;
      }
    }
    __syncthreads();

#pragma unroll
    for (int p = 0; p < 4; ++p) {
      floatx4 sT[2] = {(floatx4){0.f, 0.f, 0.f, 0.f}, (floatx4){0.f, 0.f, 0.f, 0.f}};
#pragma unroll
      for (int c = 0; c < 2; ++c) {
        const half8 kA = *(const half8*)&Kf[p * 16 + l15][c * 32 + quad * 8];
#pragma unroll
        for (int mp = 0; mp < 2; ++mp)
          sT[mp] = mfma16(kA, qB[mp][c], sT[mp]);
      }
      half4 vA[4];
#pragma unroll
      for (int dblk = 0; dblk < 4; ++dblk)
        vA[dblk] = *(const half4*)&Vt[dblk * 16 + l15][p * 16 + quad * 4];
      const int kg = k0 + p * 16 + quad * 4;
#pragma unroll
      for (int mp = 0; mp < 2; ++mp) {
        half4 eB;
#pragma unroll
        for (int r = 0; r < 4; ++r) {
          const float e = (kg + r < seq) ? __expf(sT[mp][r] * 0.125f) : 0.f;
          eB[r] = (_Float16)e;
        }
        lacc[mp] = mfma16k16(onesA, eB, lacc[mp]);
#pragma unroll
        for (int dblk = 0; dblk < 4; ++dblk)
          oacc[mp][dblk] = mfma16k16(vA[dblk], eB, oacc[mp][dblk]);
      }
    }
  }

  __syncthreads();   // K/V LDS done — reuse as Ot

  // Epilogue: per-wave O^T -> O transpose through LDS, f16 global write.
#pragma unroll
  for (int mp = 0; mp < 2; ++mp) {
#pragma unroll
    for (int dblk = 0; dblk < 4; ++dblk)
      *(floatx4*)&Ot[wv * 16 + l15][dblk * 16 + quad * 4] = oacc[mp][dblk];
    const int ql = lane >> 2;
    const int dseg = (lane & 3) * 4;
    const int qg = q0 + wv * 32 + mp * 16 + ql;
    if (qg < seq) {
      _Float16* op = &oP[((size_t)(b * seq + qg)) * 512 + h * 64];
#pragma unroll
      for (int u = 0; u < 4; ++u) {
        const float4 v = *(const float4*)&Ot[wv * 16 + ql][u * 16 + dseg];
        half4 hv;
        hv[0] = (_Float16)v.x; hv[1] = (_Float16)v.y;
        hv[2] = (_Float16)v.z; hv[3] = (_Float16)v.w;
        *(half4*)(op + u * 16 + dseg) = hv;
      }
    }
    if (quad == 0) {
      const int qg2 = q0 + wv * 32 + mp * 16 + l15;
      if (qg2 < seq)
        lP[((size_t)(b * TH + h)) * 2048 + qg2] = lacc[mp][0];
    }
  }
}

// ---------------------------------------------------------------------------
// attn pass2 (plain f16 MFMA), q-tile 64 x k-tile 128; Linv = 1/(sum_z l_z).
// ---------------------------------------------------------------------------
__global__ __launch_bounds__(256)
void attn2_mfma(const _Float16* __restrict__ qkv,
                const float* __restrict__ lb,
                float* __restrict__ outb, const int* __restrict__ mi,
                int seq_slot, int off_slot)
{
  const int seq = mi[seq_slot];
  const int q0 = blockIdx.y * 64;
  const int k0 = blockIdx.x * 128;
  if (q0 >= seq || k0 >= seq) return;
  const int b = blockIdx.z;
  const int woff = mi[off_slot];
  float* wout = outb + (size_t)woff + (size_t)b * seq * seq;

  __shared__ _Float16 Qs[64][72];
  __shared__ _Float16 Ksh[128][72];
  __shared__ float Linv[64];

  const int t = threadIdx.x;
  const int wv = t >> 6;
  const int lane = t & 63;
  const int l15 = lane & 15;
  const int quad = lane >> 4;
  const int srowQ = t >> 2;
  const int ssegQ = (t & 3) * 16;
  const int srowK = t >> 1;
  const int ssegK = (t & 1) * 32;

  floatx4 acc[8];
#pragma unroll
  for (int j = 0; j < 8; ++j) acc[j] = (floatx4){0.f, 0.f, 0.f, 0.f};

  for (int h = 0; h < TH; ++h) {
    __syncthreads();
    {
      const int qr = q0 + srowQ;
      half8 q0v = {}, q1v = {};
      if (qr < seq) {
        const _Float16* base = &qkv[((size_t)(b * seq + qr)) * 1536 + h * 64 + ssegQ];
        q0v = *(const half8*)base;
        q1v = *(const half8*)(base + 8);
      }
      *(half8*)&Qs[srowQ][ssegQ] = q0v;
      *(half8*)&Qs[srowQ][ssegQ + 8] = q1v;

      const int kr = k0 + srowK;
#pragma unroll
      for (int u = 0; u < 4; ++u) {
        half8 kv = {};
        if (kr < seq)
          kv = *(const half8*)&qkv[((size_t)(b * seq + kr)) * 1536 + 512 + h * 64 + ssegK + u * 8];
        *(half8*)&Ksh[srowK][ssegK + u * 8] = kv;
      }
      if (t < 64) {
        float lv = 1.f;
        if (q0 + t < seq) {
          const size_t lidx = ((size_t)(b * TH + h)) * 2048 + q0 + t;
          float lt = 0.f;
#pragma unroll
          for (int z = 0; z < KC; ++z) lt += lb[(size_t)z * 32768 + lidx];
          lv = lt;
        }
        Linv[t] = 1.f / lv;
      }
    }
    __syncthreads();

    half8 af[2];
#pragma unroll
    for (int c = 0; c < 2; ++c)
      af[c] = *(const half8*)&Qs[wv * 16 + l15][c * 32 + quad * 8];
    float lv[4];
#pragma unroll
    for (int r = 0; r < 4; ++r)
      lv[r] = Linv[wv * 16 + quad * 4 + r];

#pragma unroll
    for (int np = 0; np < 8; ++np) {
      half8 bf[2];
#pragma unroll
      for (int c = 0; c < 2; ++c)
        bf[c] = *(const half8*)&Ksh[np * 16 + l15][c * 32 + quad * 8];
      floatx4 s = (floatx4){0.f, 0.f, 0.f, 0.f};
      s = mfma16(af[0], bf[0], s);
      s = mfma16(af[1], bf[1], s);
#pragma unroll
      for (int r = 0; r < 4; ++r)
        acc[np][r] += __expf(s[r] * 0.125f) * lv[r];
    }
  }

#pragma unroll
  for (int r = 0; r < 4; ++r) {
    const int qg = q0 + wv * 16 + quad * 4 + r;
    if (qg >= seq) continue;
    float* rowp = wout + (size_t)qg * seq;
#pragma unroll
    for (int np = 0; np < 8; ++np) {
      const int col = k0 + np * 16 + l15;
      if (col < seq) rowp[col] = acc[np][r] * 0.125f;
    }
  }
}

// ---------------------------------------------------------------------------
__global__ __launch_bounds__(256)
void merge_kernel(const float* __restrict__ src, float* __restrict__ dst,
                  const int* __restrict__ start, const float* __restrict__ cnt,
                  const int* __restrict__ mi, int seqin_slot, int seqout_slot)
{
  const int j = blockIdx.x;
  const int b = blockIdx.y;
  const int seqo = mi[seqout_slot];
  if (j >= seqo) return;
  const int seqi = mi[seqin_slot];
  const int s = start[j];
  const float cf = cnt[j];
  const int n = (int)cf;
  const int d0 = threadIdx.x * 2;
  float s0 = 0.f, s1 = 0.f;
  const float* p = &src[((size_t)b * seqi + s) * TD + d0];
  for (int i = 0; i < n; ++i) {
    const float2 v = *(const float2*)p;
    s0 += v.x; s1 += v.y;
    p += TD;
  }
  const float inv = 1.f / (cf + 1e-10f);
  float2 o; o.x = s0 * inv; o.y = s1 * inv;
  *(float2*)&dst[((size_t)b * seqo + j) * TD + d0] = o;
}

__global__ __launch_bounds__(256)
void expand_kernel(const float* __restrict__ gout, float* __restrict__ dout,
                   const int* __restrict__ gmap, const int* __restrict__ mi)
{
  const int j = blockIdx.x;
  const int b = blockIdx.y;
  const int ntok = mi[MI_NTOK];
  if (j >= ntok) return;
  const int m2 = mi[MI_M2];
  const int g = gmap[j];
  const int d0 = threadIdx.x * 2;
  const float2 v = *(const float2*)&gout[((size_t)b * m2 + g) * TD + d0];
  *(float2*)&dout[((size_t)b * ntok + j) * TD + d0] = v;
}

// ---------------------------------------------------------------------------
extern "C" void kernel_launch(void* const* d_in, const int* in_sizes, int n_in,
                              void* d_out, int out_size, void* d_ws, size_t ws_size,
                              hipStream_t stream)
{
  const float* x   = (const float*)d_in[0];
  const float* cWi = (const float*)d_in[1];
  const float* cbi = (const float*)d_in[2];
  const float* cWo = (const float*)d_in[3];
  const float* cbo = (const float*)d_in[4];
  const float* bWi = (const float*)d_in[5];
  const float* bbi = (const float*)d_in[6];
  const float* bWo = (const float*)d_in[7];
  const float* bbo = (const float*)d_in[8];
  const float* gWi = (const float*)d_in[9];
  const float* gbi = (const float*)d_in[10];
  const float* gWo = (const float*)d_in[11];
  const float* gbo = (const float*)d_in[12];
  const float* mw  = (const float*)d_in[13];
  const float* mbv = (const float*)d_in[14];
  const float* gw  = (const float*)d_in[15];
  const float* gbv = (const float*)d_in[16];
  float* outf = (float*)d_out;

  char* wsb = (char*)d_ws;
  int*   mi     = (int*)(wsb);
  int*   start1 = (int*)(wsb + 1024);
  float* cnt1   = (float*)(wsb + 1024 + 8192);
  int*   start2 = (int*)(wsb + 1024 + 2 * 8192);
  float* cnt2   = (float*)(wsb + 1024 + 3 * 8192);
  int*   gmap   = (int*)(wsb + 1024 + 4 * 8192);
  float* lbase  = (float*)(wsb + 65536);               // KC x 32768 f32 (512 KB)
  _Float16* qkv = (_Float16*)(wsb + 655360);           // 4096x1536 f16 (12.6 MB)
  _Float16* Obase = (_Float16*)(wsb + 655360 + 12582912);   // KC x 4 MB f16
  float* stg_o  = (float*)(wsb + 655360 + 12582912 + (size_t)KC * 4194304);  // 8 MB
  float* stg_m  = stg_o + 2097152;                     // 8 MB  (total ~46.8 MB)

  const dim3 blk(256);

  meta_kernel<<<dim3(1), blk, 0, stream>>>(mw, mbv, gw, gbv, mi, start1, cnt1, start2, cnt2, gmap);

  // ---- char stage ----
  gemm_mfma<_Float16><<<dim3(24, 32), blk, 0, stream>>>(x, cWi, cbi, qkv, mi, MI_MCHAR, 1536);
  attn1_mfma<<<dim3(16, 16, KC), blk, 0, stream>>>(qkv, lbase, Obase, mi, MI_SEQC);
  attn2_mfma<<<dim3(16, 32, 2), blk, 0, stream>>>(qkv, lbase, outf, mi, MI_SEQC, MI_OFF_CW);
  gemm_norm_mfma<<<dim3(8, 32), blk, 0, stream>>>(Obase, lbase, cWo, cbo, stg_o, mi, MI_MCHAR, MI_SEQC);
  merge_kernel<<<dim3(2048, 2), blk, 0, stream>>>(stg_o, stg_m, start1, cnt1, mi, MI_SEQC, MI_SEQB);

  // ---- block stage ----
  gemm_mfma<_Float16><<<dim3(24, 32), blk, 0, stream>>>(stg_m, bWi, bbi, qkv, mi, MI_MBLOCK, 1536);
  attn1_mfma<<<dim3(16, 16, KC), blk, 0, stream>>>(qkv, lbase, Obase, mi, MI_SEQB);
  attn2_mfma<<<dim3(16, 32, 2), blk, 0, stream>>>(qkv, lbase, outf, mi, MI_SEQB, MI_OFF_BW);
  gemm_norm_mfma<<<dim3(8, 32), blk, 0, stream>>>(Obase, lbase, bWo, bbo, stg_o, mi, MI_MBLOCK, MI_SEQB);
  merge_kernel<<<dim3(2048, 2), blk, 0, stream>>>(stg_o, stg_m, start2, cnt2, mi, MI_SEQB, MI_SEQG);

  // ---- glob stage ----
  gemm_mfma<_Float16><<<dim3(24, 32), blk, 0, stream>>>(stg_m, gWi, gbi, qkv, mi, MI_MGLOB, 1536);
  attn1_mfma<<<dim3(16, 16, KC), blk, 0, stream>>>(qkv, lbase, Obase, mi, MI_SEQG);
  attn2_mfma<<<dim3(16, 32, 2), blk, 0, stream>>>(qkv, lbase, outf, mi, MI_SEQG, MI_OFF_GW);
  gemm_norm_mfma<<<dim3(8, 32), blk, 0, stream>>>(Obase, lbase, gWo, gbo, stg_o, mi, MI_MGLOB, MI_SEQG);
  expand_kernel<<<dim3(2048, 2), blk, 0, stream>>>(stg_o, outf, gmap, mi);

  (void)in_sizes; (void)n_in; (void)out_size; (void)ws_size;
}

// Round 11
// 427.576 us; speedup vs baseline: 1.1429x; 1.1429x over previous
//
#include <hip/hip_runtime.h>
#include <cstdint>
#include <cstddef>

// DynamicHierarchicalAttention — MFMA pipeline.
// R10: gemm_norm retiled 64x64 (grid 512 = 2 blocks/CU — R9's 256-block
// version was latency-starved at 1 block/CU: MfmaUtil 3.6%, occ 10%),
// A-partials loaded as half8.  attn1 split-K x4 + S^T trick (R8/R9),
// qkv f16 (R5), GEMMs split-f16 (fp32-grade).

#define TB 2
#define TT 2048
#define TD 512
#define TH 8
#define THD 64
#define KC 4   // k-chunks in attn1

#define MI_M1 0
#define MI_M2 1
#define MI_NTOK 2
#define MI_OFF_CW 3
#define MI_OFF_BW 4
#define MI_OFF_GW 5
#define MI_MCHAR 6
#define MI_MBLOCK 7
#define MI_MGLOB 8
#define MI_SEQC 9
#define MI_SEQB 10
#define MI_SEQG 11

typedef _Float16 half8 __attribute__((ext_vector_type(8)));
typedef _Float16 half4 __attribute__((ext_vector_type(4)));
typedef _Float16 half2_t __attribute__((ext_vector_type(2)));
typedef float floatx4 __attribute__((ext_vector_type(4)));

__device__ __forceinline__ floatx4 mfma16(half8 a, half8 b, floatx4 c) {
  return __builtin_amdgcn_mfma_f32_16x16x32_f16(a, b, c, 0, 0, 0);
}
__device__ __forceinline__ floatx4 mfma16k16(half4 a, half4 b, floatx4 c) {
  return __builtin_amdgcn_mfma_f32_16x16x16f16(a, b, c, 0, 0, 0);
}

__device__ __forceinline__ double fracd(double x) { return x - floor(x); }

// ---------------------------------------------------------------------------
// parallel boundary scan for one phase: n elements, increment c.
// ---------------------------------------------------------------------------
__device__ int scan_phase(int n, double c, int* __restrict__ ids,
                          int* __restrict__ startg, float* __restrict__ cntg,
                          int* __restrict__ wsum, int t)
{
  int loc[8];
  const int base = t * 8;
#pragma unroll
  for (int j = 0; j < 8; ++j) {
    const int i = base + j;
    int f = 0;
    if (i < n) {
      const int pidx = (i == 0) ? n : i;   // roll: prev of elem 0 is elem n-1
      f = (fracd((double)(i + 1) * c) < fracd((double)pidx * c)) ? 1 : 0;
    }
    loc[j] = f + ((j > 0) ? loc[j - 1] : 0);
  }
  wsum[t] = loc[7];
  __syncthreads();
  for (int off = 1; off < 256; off <<= 1) {
    int u = 0;
    if (t >= off) u = wsum[t - off];
    __syncthreads();
    wsum[t] += u;
    __syncthreads();
  }
  const int excl = wsum[t] - loc[7];
  const int m = wsum[255];
#pragma unroll
  for (int j = 0; j < 8; ++j) {
    const int i = base + j;
    if (i < n) {
      const int id = excl + loc[j];
      ids[i] = id;
      const int f = loc[j] - ((j > 0) ? loc[j - 1] : 0);
      if (f) startg[id - 1] = i;
    }
  }
  __syncthreads();
  for (int j = t; j < m; j += 256)
    cntg[j] = (float)((((j + 1) < m) ? startg[j + 1] : n) - startg[j]);
  __syncthreads();
  return m;
}

// ---------------------------------------------------------------------------
__global__ __launch_bounds__(256)
void meta_kernel(const float* __restrict__ mw, const float* __restrict__ mb,
                 const float* __restrict__ gw, const float* __restrict__ gb,
                 int* __restrict__ mi,
                 int* __restrict__ start1, float* __restrict__ cnt1,
                 int* __restrict__ start2, float* __restrict__ cnt2,
                 int* __restrict__ gmap)
{
  __shared__ int ids1[TT];
  __shared__ int ids2[TT];
  __shared__ int wsum[256];
  __shared__ double dsh[256];
  const int t = threadIdx.x;

  double s1 = 0.0, s2 = 0.0;
  for (int i = t; i < TD; i += 256) { s1 += (double)mw[i]; s2 += (double)gw[i]; }
  dsh[t] = s1; __syncthreads();
  for (int off = 128; off > 0; off >>= 1) {
    if (t < off) dsh[t] += dsh[t + off];
    __syncthreads();
  }
  const double c1 = dsh[0] + (double)mb[0];
  __syncthreads();
  dsh[t] = s2; __syncthreads();
  for (int off = 128; off > 0; off >>= 1) {
    if (t < off) dsh[t] += dsh[t + off];
    __syncthreads();
  }
  const double c2 = dsh[0] + (double)gb[0];
  __syncthreads();

  const int m1 = scan_phase(TT, c1, ids1, start1, cnt1, wsum, t);
  const int m2 = scan_phase(m1, c2, ids2, start2, cnt2, wsum, t);

  int i0 = TT;
  if (m1 >= 1 && m2 >= 1) i0 = start1[start2[0]];
  const int ntok = TT - i0;

  if (t == 0) {
    mi[MI_M1] = m1; mi[MI_M2] = m2; mi[MI_NTOK] = ntok;
    const int offcw = TB * ntok * TD;
    mi[MI_OFF_CW] = offcw;
    mi[MI_OFF_BW] = offcw + TB * TT * TT;
    mi[MI_OFF_GW] = offcw + TB * TT * TT + TB * m1 * m1;
    mi[MI_MCHAR] = TB * TT;
    mi[MI_MBLOCK] = TB * m1;
    mi[MI_MGLOB] = TB * m2;
    mi[MI_SEQC] = TT;
    mi[MI_SEQB] = m1;
    mi[MI_SEQG] = m2;
  }
  for (int i = i0 + t; i < TT; i += 256)
    gmap[i - i0] = ids2[ids1[i] - 1] - 1;
}

// ---------------------------------------------------------------------------
// GEMM 128m x 64n tile: C[M,N] = A[M,512] @ W[N,512]^T + bias, split-f16.
// ---------------------------------------------------------------------------
template <typename OutT>
__global__ __launch_bounds__(256)
void gemm_mfma(const float* __restrict__ A, const float* __restrict__ W,
               const float* __restrict__ bias, OutT* __restrict__ C,
               const int* __restrict__ mi, int m_slot, int N)
{
  const int M = mi[m_slot];
  const int bm = blockIdx.y * 128;
  if (bm >= M) return;
  const int bn = blockIdx.x * 64;
  __shared__ _Float16 Ah[128][40];
  __shared__ _Float16 Al[128][40];
  __shared__ _Float16 Wh[64][40];
  __shared__ _Float16 Wl[64][40];

  const int t = threadIdx.x;
  const int wv = t >> 6;
  const int lane = t & 63;
  const int l15 = lane & 15;
  const int quad = lane >> 4;
  const int srowA = t >> 1;
  const int ssegA = (t & 1) * 16;
  const int srowW = t >> 2;
  const int ssegW = (t & 3) * 8;

  floatx4 acc[2][4];
#pragma unroll
  for (int i = 0; i < 2; ++i)
#pragma unroll
    for (int j = 0; j < 4; ++j) acc[i][j] = (floatx4){0.f, 0.f, 0.f, 0.f};

  for (int kk = 0; kk < TD; kk += 32) {
    __syncthreads();
    {
      const int ar = bm + srowA;
#pragma unroll
      for (int u = 0; u < 4; ++u) {
        float4 av = make_float4(0.f, 0.f, 0.f, 0.f);
        if (ar < M) av = *(const float4*)&A[(size_t)ar * TD + kk + ssegA + u * 4];
        const float aa[4] = {av.x, av.y, av.z, av.w};
        half4 hi, lo;
#pragma unroll
        for (int e = 0; e < 4; ++e) {
          const _Float16 h = (_Float16)aa[e];
          hi[e] = h; lo[e] = (_Float16)(aa[e] - (float)h);
        }
        *(half4*)&Ah[srowA][ssegA + u * 4] = hi;
        *(half4*)&Al[srowA][ssegA + u * 4] = lo;
      }
#pragma unroll
      for (int u = 0; u < 2; ++u) {
        const float4 wvv = *(const float4*)&W[(size_t)(bn + srowW) * TD + kk + ssegW + u * 4];
        const float ww[4] = {wvv.x, wvv.y, wvv.z, wvv.w};
        half4 hi, lo;
#pragma unroll
        for (int e = 0; e < 4; ++e) {
          const _Float16 h = (_Float16)ww[e];
          hi[e] = h; lo[e] = (_Float16)(ww[e] - (float)h);
        }
        *(half4*)&Wh[srowW][ssegW + u * 4] = hi;
        *(half4*)&Wl[srowW][ssegW + u * 4] = lo;
      }
    }
    __syncthreads();
    half8 ah[2], al[2];
#pragma unroll
    for (int mp = 0; mp < 2; ++mp) {
      ah[mp] = *(const half8*)&Ah[wv * 32 + mp * 16 + l15][quad * 8];
      al[mp] = *(const half8*)&Al[wv * 32 + mp * 16 + l15][quad * 8];
    }
#pragma unroll
    for (int np = 0; np < 4; ++np) {
      const half8 bh = *(const half8*)&Wh[np * 16 + l15][quad * 8];
      const half8 bl = *(const half8*)&Wl[np * 16 + l15][quad * 8];
#pragma unroll
      for (int mp = 0; mp < 2; ++mp) {
        acc[mp][np] = mfma16(al[mp], bh, acc[mp][np]);
        acc[mp][np] = mfma16(ah[mp], bl, acc[mp][np]);
        acc[mp][np] = mfma16(ah[mp], bh, acc[mp][np]);
      }
    }
  }
  float bv[4];
#pragma unroll
  for (int np = 0; np < 4; ++np) bv[np] = bias[bn + np * 16 + l15];
#pragma unroll
  for (int mp = 0; mp < 2; ++mp) {
#pragma unroll
    for (int r = 0; r < 4; ++r) {
      const int row = bm + wv * 32 + mp * 16 + quad * 4 + r;
      if (row < M) {
        OutT* cp = &C[(size_t)row * N + bn];
#pragma unroll
        for (int np = 0; np < 4; ++np)
          cp[np * 16 + l15] = (OutT)(acc[mp][np][r] + bv[np]);
      }
    }
  }
}

// ---------------------------------------------------------------------------
// Proj GEMM with fused combine, 64m x 64n tile (grid 2 blocks/CU):
// A-row = (sum_z O_z f16) * 1/(sum_z l_z); A staged split hi/lo.
// ---------------------------------------------------------------------------
__global__ __launch_bounds__(256)
void gemm_norm_mfma(const _Float16* __restrict__ Ob, const float* __restrict__ lb,
                    const float* __restrict__ W, const float* __restrict__ bias,
                    float* __restrict__ C, const int* __restrict__ mi,
                    int m_slot, int seq_slot)
{
  const int M = mi[m_slot];
  const int bm = blockIdx.y * 64;
  if (bm >= M) return;
  const int seq = mi[seq_slot];
  const int bn = blockIdx.x * 64;
  __shared__ _Float16 Ah[64][40];
  __shared__ _Float16 Al[64][40];
  __shared__ _Float16 Wh[64][40];
  __shared__ _Float16 Wl[64][40];

  const int t = threadIdx.x;
  const int wv = t >> 6;
  const int lane = t & 63;
  const int l15 = lane & 15;
  const int quad = lane >> 4;
  const int srow = t >> 2;
  const int sseg = (t & 3) * 8;

  const int ar = bm + srow;
  const int ab = (ar >= seq) ? 1 : 0;
  const int aq = ar - ab * seq;

  floatx4 acc[4];
#pragma unroll
  for (int j = 0; j < 4; ++j) acc[j] = (floatx4){0.f, 0.f, 0.f, 0.f};

  for (int kk = 0; kk < TD; kk += 32) {
    __syncthreads();
    {
      // A stage: 64 rows x 32 k, 8 elems/thread, half8 per z-stream.
      float aa[8] = {0.f, 0.f, 0.f, 0.f, 0.f, 0.f, 0.f, 0.f};
      if (ar < M) {
        const size_t off = (size_t)ar * TD + kk + sseg;
#pragma unroll
        for (int z = 0; z < KC; ++z) {
          const half8 hv = *(const half8*)&Ob[(size_t)z * 2097152 + off];
#pragma unroll
          for (int e = 0; e < 8; ++e) aa[e] += (float)hv[e];
        }
        const int h = kk >> 6;
        const size_t lidx = ((size_t)(ab * TH + h)) * 2048 + aq;
        float lt = 0.f;
#pragma unroll
        for (int z = 0; z < KC; ++z) lt += lb[(size_t)z * 32768 + lidx];
        const float linv = 1.f / lt;
#pragma unroll
        for (int e = 0; e < 8; ++e) aa[e] *= linv;
      }
      half8 hi, lo;
#pragma unroll
      for (int e = 0; e < 8; ++e) {
        const _Float16 h = (_Float16)aa[e];
        hi[e] = h; lo[e] = (_Float16)(aa[e] - (float)h);
      }
      *(half8*)&Ah[srow][sseg] = hi;
      *(half8*)&Al[srow][sseg] = lo;

      // W stage: 64 rows x 32 k f32.
      const float4 w0 = *(const float4*)&W[(size_t)(bn + srow) * TD + kk + sseg];
      const float4 w1 = *(const float4*)&W[(size_t)(bn + srow) * TD + kk + sseg + 4];
      const float ww[8] = {w0.x, w0.y, w0.z, w0.w, w1.x, w1.y, w1.z, w1.w};
      half8 whi, wlo;
#pragma unroll
      for (int e = 0; e < 8; ++e) {
        const _Float16 h = (_Float16)ww[e];
        whi[e] = h; wlo[e] = (_Float16)(ww[e] - (float)h);
      }
      *(half8*)&Wh[srow][sseg] = whi;
      *(half8*)&Wl[srow][sseg] = wlo;
    }
    __syncthreads();
    const half8 ah = *(const half8*)&Ah[wv * 16 + l15][quad * 8];
    const half8 al = *(const half8*)&Al[wv * 16 + l15][quad * 8];
#pragma unroll
    for (int np = 0; np < 4; ++np) {
      const half8 bh = *(const half8*)&Wh[np * 16 + l15][quad * 8];
      const half8 bl = *(const half8*)&Wl[np * 16 + l15][quad * 8];
      acc[np] = mfma16(al, bh, acc[np]);
      acc[np] = mfma16(ah, bl, acc[np]);
      acc[np] = mfma16(ah, bh, acc[np]);
    }
  }
  float bv[4];
#pragma unroll
  for (int np = 0; np < 4; ++np) bv[np] = bias[bn + np * 16 + l15];
#pragma unroll
  for (int r = 0; r < 4; ++r) {
    const int row = bm + wv * 16 + quad * 4 + r;
    if (row < M) {
      float* cp = &C[(size_t)row * 512 + bn];
#pragma unroll
      for (int np = 0; np < 4; ++np)
        cp[np * 16 + l15] = acc[np][r] + bv[np];
    }
  }
}

// ---------------------------------------------------------------------------
// attn pass1, split-K x4 (z = chunk), S^T-trick.  q-tile 128, 4 waves x 32 q.
// Partials: O_z f16 (unnormalized), l_z f32.
// ---------------------------------------------------------------------------
__global__ __launch_bounds__(256)
void attn1_mfma(const _Float16* __restrict__ qkv,
                float* __restrict__ lbase, _Float16* __restrict__ Obase,
                const int* __restrict__ mi, int seq_slot)
{
  const int seq = mi[seq_slot];
  const int q0 = blockIdx.x * 128;
  if (q0 >= seq) return;
  const int b = blockIdx.y >> 3, h = blockIdx.y & 7;
  const int z = blockIdx.z;
  float* lP = lbase + (size_t)z * 32768;
  _Float16* oP = Obase + (size_t)z * 2097152;
  const int t = threadIdx.x;
  const int wv = t >> 6;
  const int lane = t & 63;
  const int l15 = lane & 15;
  const int quad = lane >> 4;

  __shared__ __align__(16) char smem_raw[18432];
  _Float16 (*Kf)[72] = (_Float16 (*)[72])smem_raw;              // 64x72 f16
  _Float16 (*Vt)[72] = (_Float16 (*)[72])(smem_raw + 9216);     // 64x72 f16
  float    (*Ot)[68] = (float (*)[68])smem_raw;                 // epilogue reuse

  half8 qB[2][2];
#pragma unroll
  for (int mp = 0; mp < 2; ++mp) {
    const int qrow = q0 + wv * 32 + mp * 16 + l15;
#pragma unroll
    for (int c = 0; c < 2; ++c) {
      half8 v = {};
      if (qrow < seq)
        v = *(const half8*)&qkv[((size_t)(b * seq + qrow)) * 1536 + h * 64 + c * 32 + quad * 8];
      qB[mp][c] = v;
    }
  }
  half4 onesA;
#pragma unroll
  for (int j = 0; j < 4; ++j) onesA[j] = (_Float16)1.0f;

  floatx4 oacc[2][4];
#pragma unroll
  for (int i = 0; i < 2; ++i)
#pragma unroll
    for (int j = 0; j < 4; ++j) oacc[i][j] = (floatx4){0.f, 0.f, 0.f, 0.f};
  floatx4 lacc[2] = {(floatx4){0.f, 0.f, 0.f, 0.f}, (floatx4){0.f, 0.f, 0.f, 0.f}};

  const int nkt = (seq + 63) >> 6;
  const int nkc = (nkt + KC - 1) / KC;
  const int kt_beg = z * nkc;
  const int kt_end = min(kt_beg + nkc, nkt);

  for (int kt = kt_beg; kt < kt_end; ++kt) {
    const int k0 = kt * 64;
    __syncthreads();
    {
      const int row = t >> 2;
      const int seg = (t & 3) * 16;
      const int kg = k0 + row;
      half8 v0 = {}, v1 = {};
      if (kg < seq) {
        const _Float16* base = &qkv[((size_t)(b * seq + kg)) * 1536 + 512 + h * 64 + seg];
        v0 = *(const half8*)base;
        v1 = *(const half8*)(base + 8);
      }
      *(half8*)&Kf[row][seg] = v0;
      *(half8*)&Kf[row][seg + 8] = v1;
    }
    {
      const int tp = lane & 31;
      const int dsel = lane >> 5;
      const int dbase = wv * 16 + dsel * 8;
      const int kg0 = k0 + tp * 2;
      half8 vA = {}, vB = {};
      if (kg0 < seq)
        vA = *(const half8*)&qkv[((size_t)(b * seq + kg0)) * 1536 + 1024 + h * 64 + dbase];
      if (kg0 + 1 < seq)
        vB = *(const half8*)&qkv[((size_t)(b * seq + kg0 + 1)) * 1536 + 1024 + h * 64 + dbase];
#pragma unroll
      for (int j = 0; j < 8; ++j) {
        half2_t pk; pk[0] = vA[j]; pk[1] = vB[j];
        *(half2_t*)&Vt[dbase + j][tp * 2] = pk;
      }
    }
    __syncthreads();

#pragma unroll
    for (int p = 0; p < 4; ++p) {
      floatx4 sT[2] = {(floatx4){0.f, 0.f, 0.f, 0.f}, (floatx4){0.f, 0.f, 0.f, 0.f}};
#pragma unroll
      for (int c = 0; c < 2; ++c) {
        const half8 kA = *(const half8*)&Kf[p * 16 + l15][c * 32 + quad * 8];
#pragma unroll
        for (int mp = 0; mp < 2; ++mp)
          sT[mp] = mfma16(kA, qB[mp][c], sT[mp]);
      }
      half4 vA[4];
#pragma unroll
      for (int dblk = 0; dblk < 4; ++dblk)
        vA[dblk] = *(const half4*)&Vt[dblk * 16 + l15][p * 16 + quad * 4];
      const int kg = k0 + p * 16 + quad * 4;
#pragma unroll
      for (int mp = 0; mp < 2; ++mp) {
        half4 eB;
#pragma unroll
        for (int r = 0; r < 4; ++r) {
          const float e = (kg + r < seq) ? __expf(sT[mp][r] * 0.125f) : 0.f;
          eB[r] = (_Float16)e;
        }
        lacc[mp] = mfma16k16(onesA, eB, lacc[mp]);
#pragma unroll
        for (int dblk = 0; dblk < 4; ++dblk)
          oacc[mp][dblk] = mfma16k16(vA[dblk], eB, oacc[mp][dblk]);
      }
    }
  }

  __syncthreads();   // K/V LDS done — reuse as Ot

#pragma unroll
  for (int mp = 0; mp < 2; ++mp) {
#pragma unroll
    for (int dblk = 0; dblk < 4; ++dblk)
      *(floatx4*)&Ot[wv * 16 + l15][dblk * 16 + quad * 4] = oacc[mp][dblk];
    const int ql = lane >> 2;
    const int dseg = (lane & 3) * 4;
    const int qg = q0 + wv * 32 + mp * 16 + ql;
    if (qg < seq) {
      _Float16* op = &oP[((size_t)(b * seq + qg)) * 512 + h * 64];
#pragma unroll
      for (int u = 0; u < 4; ++u) {
        const float4 v = *(const float4*)&Ot[wv * 16 + ql][u * 16 + dseg];
        half4 hv;
        hv[0] = (_Float16)v.x; hv[1] = (_Float16)v.y;
        hv[2] = (_Float16)v.z; hv[3] = (_Float16)v.w;
        *(half4*)(op + u * 16 + dseg) = hv;
      }
    }
    if (quad == 0) {
      const int qg2 = q0 + wv * 32 + mp * 16 + l15;
      if (qg2 < seq)
        lP[((size_t)(b * TH + h)) * 2048 + qg2] = lacc[mp][0];
    }
  }
}

// ---------------------------------------------------------------------------
// attn pass2 (plain f16 MFMA), q-tile 64 x k-tile 128; Linv = 1/(sum_z l_z).
// ---------------------------------------------------------------------------
__global__ __launch_bounds__(256)
void attn2_mfma(const _Float16* __restrict__ qkv,
                const float* __restrict__ lb,
                float* __restrict__ outb, const int* __restrict__ mi,
                int seq_slot, int off_slot)
{
  const int seq = mi[seq_slot];
  const int q0 = blockIdx.y * 64;
  const int k0 = blockIdx.x * 128;
  if (q0 >= seq || k0 >= seq) return;
  const int b = blockIdx.z;
  const int woff = mi[off_slot];
  float* wout = outb + (size_t)woff + (size_t)b * seq * seq;

  __shared__ _Float16 Qs[64][72];
  __shared__ _Float16 Ksh[128][72];
  __shared__ float Linv[64];

  const int t = threadIdx.x;
  const int wv = t >> 6;
  const int lane = t & 63;
  const int l15 = lane & 15;
  const int quad = lane >> 4;
  const int srowQ = t >> 2;
  const int ssegQ = (t & 3) * 16;
  const int srowK = t >> 1;
  const int ssegK = (t & 1) * 32;

  floatx4 acc[8];
#pragma unroll
  for (int j = 0; j < 8; ++j) acc[j] = (floatx4){0.f, 0.f, 0.f, 0.f};

  for (int h = 0; h < TH; ++h) {
    __syncthreads();
    {
      const int qr = q0 + srowQ;
      half8 q0v = {}, q1v = {};
      if (qr < seq) {
        const _Float16* base = &qkv[((size_t)(b * seq + qr)) * 1536 + h * 64 + ssegQ];
        q0v = *(const half8*)base;
        q1v = *(const half8*)(base + 8);
      }
      *(half8*)&Qs[srowQ][ssegQ] = q0v;
      *(half8*)&Qs[srowQ][ssegQ + 8] = q1v;

      const int kr = k0 + srowK;
#pragma unroll
      for (int u = 0; u < 4; ++u) {
        half8 kv = {};
        if (kr < seq)
          kv = *(const half8*)&qkv[((size_t)(b * seq + kr)) * 1536 + 512 + h * 64 + ssegK + u * 8];
        *(half8*)&Ksh[srowK][ssegK + u * 8] = kv;
      }
      if (t < 64) {
        float lv = 1.f;
        if (q0 + t < seq) {
          const size_t lidx = ((size_t)(b * TH + h)) * 2048 + q0 + t;
          float lt = 0.f;
#pragma unroll
          for (int z = 0; z < KC; ++z) lt += lb[(size_t)z * 32768 + lidx];
          lv = lt;
        }
        Linv[t] = 1.f / lv;
      }
    }
    __syncthreads();

    half8 af[2];
#pragma unroll
    for (int c = 0; c < 2; ++c)
      af[c] = *(const half8*)&Qs[wv * 16 + l15][c * 32 + quad * 8];
    float lv[4];
#pragma unroll
    for (int r = 0; r < 4; ++r)
      lv[r] = Linv[wv * 16 + quad * 4 + r];

#pragma unroll
    for (int np = 0; np < 8; ++np) {
      half8 bf[2];
#pragma unroll
      for (int c = 0; c < 2; ++c)
        bf[c] = *(const half8*)&Ksh[np * 16 + l15][c * 32 + quad * 8];
      floatx4 s = (floatx4){0.f, 0.f, 0.f, 0.f};
      s = mfma16(af[0], bf[0], s);
      s = mfma16(af[1], bf[1], s);
#pragma unroll
      for (int r = 0; r < 4; ++r)
        acc[np][r] += __expf(s[r] * 0.125f) * lv[r];
    }
  }

#pragma unroll
  for (int r = 0; r < 4; ++r) {
    const int qg = q0 + wv * 16 + quad * 4 + r;
    if (qg >= seq) continue;
    float* rowp = wout + (size_t)qg * seq;
#pragma unroll
    for (int np = 0; np < 8; ++np) {
      const int col = k0 + np * 16 + l15;
      if (col < seq) rowp[col] = acc[np][r] * 0.125f;
    }
  }
}

// ---------------------------------------------------------------------------
__global__ __launch_bounds__(256)
void merge_kernel(const float* __restrict__ src, float* __restrict__ dst,
                  const int* __restrict__ start, const float* __restrict__ cnt,
                  const int* __restrict__ mi, int seqin_slot, int seqout_slot)
{
  const int j = blockIdx.x;
  const int b = blockIdx.y;
  const int seqo = mi[seqout_slot];
  if (j >= seqo) return;
  const int seqi = mi[seqin_slot];
  const int s = start[j];
  const float cf = cnt[j];
  const int n = (int)cf;
  const int d0 = threadIdx.x * 2;
  float s0 = 0.f, s1 = 0.f;
  const float* p = &src[((size_t)b * seqi + s) * TD + d0];
  for (int i = 0; i < n; ++i) {
    const float2 v = *(const float2*)p;
    s0 += v.x; s1 += v.y;
    p += TD;
  }
  const float inv = 1.f / (cf + 1e-10f);
  float2 o; o.x = s0 * inv; o.y = s1 * inv;
  *(float2*)&dst[((size_t)b * seqo + j) * TD + d0] = o;
}

__global__ __launch_bounds__(256)
void expand_kernel(const float* __restrict__ gout, float* __restrict__ dout,
                   const int* __restrict__ gmap, const int* __restrict__ mi)
{
  const int j = blockIdx.x;
  const int b = blockIdx.y;
  const int ntok = mi[MI_NTOK];
  if (j >= ntok) return;
  const int m2 = mi[MI_M2];
  const int g = gmap[j];
  const int d0 = threadIdx.x * 2;
  const float2 v = *(const float2*)&gout[((size_t)b * m2 + g) * TD + d0];
  *(float2*)&dout[((size_t)b * ntok + j) * TD + d0] = v;
}

// ---------------------------------------------------------------------------
extern "C" void kernel_launch(void* const* d_in, const int* in_sizes, int n_in,
                              void* d_out, int out_size, void* d_ws, size_t ws_size,
                              hipStream_t stream)
{
  const float* x   = (const float*)d_in[0];
  const float* cWi = (const float*)d_in[1];
  const float* cbi = (const float*)d_in[2];
  const float* cWo = (const float*)d_in[3];
  const float* cbo = (const float*)d_in[4];
  const float* bWi = (const float*)d_in[5];
  const float* bbi = (const float*)d_in[6];
  const float* bWo = (const float*)d_in[7];
  const float* bbo = (const float*)d_in[8];
  const float* gWi = (const float*)d_in[9];
  const float* gbi = (const float*)d_in[10];
  const float* gWo = (const float*)d_in[11];
  const float* gbo = (const float*)d_in[12];
  const float* mw  = (const float*)d_in[13];
  const float* mbv = (const float*)d_in[14];
  const float* gw  = (const float*)d_in[15];
  const float* gbv = (const float*)d_in[16];
  float* outf = (float*)d_out;

  char* wsb = (char*)d_ws;
  int*   mi     = (int*)(wsb);
  int*   start1 = (int*)(wsb + 1024);
  float* cnt1   = (float*)(wsb + 1024 + 8192);
  int*   start2 = (int*)(wsb + 1024 + 2 * 8192);
  float* cnt2   = (float*)(wsb + 1024 + 3 * 8192);
  int*   gmap   = (int*)(wsb + 1024 + 4 * 8192);
  float* lbase  = (float*)(wsb + 65536);               // KC x 32768 f32 (512 KB)
  _Float16* qkv = (_Float16*)(wsb + 655360);           // 4096x1536 f16 (12.6 MB)
  _Float16* Obase = (_Float16*)(wsb + 655360 + 12582912);   // KC x 4 MB f16
  float* stg_o  = (float*)(wsb + 655360 + 12582912 + (size_t)KC * 4194304);  // 8 MB
  float* stg_m  = stg_o + 2097152;                     // 8 MB  (total ~46.8 MB)

  const dim3 blk(256);

  meta_kernel<<<dim3(1), blk, 0, stream>>>(mw, mbv, gw, gbv, mi, start1, cnt1, start2, cnt2, gmap);

  // ---- char stage ----
  gemm_mfma<_Float16><<<dim3(24, 32), blk, 0, stream>>>(x, cWi, cbi, qkv, mi, MI_MCHAR, 1536);
  attn1_mfma<<<dim3(16, 16, KC), blk, 0, stream>>>(qkv, lbase, Obase, mi, MI_SEQC);
  attn2_mfma<<<dim3(16, 32, 2), blk, 0, stream>>>(qkv, lbase, outf, mi, MI_SEQC, MI_OFF_CW);
  gemm_norm_mfma<<<dim3(8, 64), blk, 0, stream>>>(Obase, lbase, cWo, cbo, stg_o, mi, MI_MCHAR, MI_SEQC);
  merge_kernel<<<dim3(2048, 2), blk, 0, stream>>>(stg_o, stg_m, start1, cnt1, mi, MI_SEQC, MI_SEQB);

  // ---- block stage ----
  gemm_mfma<_Float16><<<dim3(24, 32), blk, 0, stream>>>(stg_m, bWi, bbi, qkv, mi, MI_MBLOCK, 1536);
  attn1_mfma<<<dim3(16, 16, KC), blk, 0, stream>>>(qkv, lbase, Obase, mi, MI_SEQB);
  attn2_mfma<<<dim3(16, 32, 2), blk, 0, stream>>>(qkv, lbase, outf, mi, MI_SEQB, MI_OFF_BW);
  gemm_norm_mfma<<<dim3(8, 64), blk, 0, stream>>>(Obase, lbase, bWo, bbo, stg_o, mi, MI_MBLOCK, MI_SEQB);
  merge_kernel<<<dim3(2048, 2), blk, 0, stream>>>(stg_o, stg_m, start2, cnt2, mi, MI_SEQB, MI_SEQG);

  // ---- glob stage ----
  gemm_mfma<_Float16><<<dim3(24, 32), blk, 0, stream>>>(stg_m, gWi, gbi, qkv, mi, MI_MGLOB, 1536);
  attn1_mfma<<<dim3(16, 16, KC), blk, 0, stream>>>(qkv, lbase, Obase, mi, MI_SEQG);
  attn2_mfma<<<dim3(16, 32, 2), blk, 0, stream>>>(qkv, lbase, outf, mi, MI_SEQG, MI_OFF_GW);
  gemm_norm_mfma<<<dim3(8, 64), blk, 0, stream>>>(Obase, lbase, gWo, gbo, stg_o, mi, MI_MGLOB, MI_SEQG);
  expand_kernel<<<dim3(2048, 2), blk, 0, stream>>>(stg_o, outf, gmap, mi);

  (void)in_sizes; (void)n_in; (void)out_size; (void)ws_size;
}

// Round 12
// 398.449 us; speedup vs baseline: 1.2264x; 1.0731x over previous
//
#include <hip/hip_runtime.h>
#include <cstdint>
#include <cstddef>

// DynamicHierarchicalAttention — MFMA pipeline.
// R11: qkv GEMM switched to plain f16 (SPLIT=false): its output is rounded
// to f16 anyway (R5), so split-f16's fp32-grade sum is wasted — 3 MFMAs -> 1,
// no hi/lo split VALU, half the staging LDS.  Proj GEMM (gemm_norm) keeps
// split-f16 (feeds the merge chain).  attn1 split-K x4 + S^T trick (R8/R9),
// gemm_norm 64x64 (R10).

#define TB 2
#define TT 2048
#define TD 512
#define TH 8
#define THD 64
#define KC 4   // k-chunks in attn1

#define MI_M1 0
#define MI_M2 1
#define MI_NTOK 2
#define MI_OFF_CW 3
#define MI_OFF_BW 4
#define MI_OFF_GW 5
#define MI_MCHAR 6
#define MI_MBLOCK 7
#define MI_MGLOB 8
#define MI_SEQC 9
#define MI_SEQB 10
#define MI_SEQG 11

typedef _Float16 half8 __attribute__((ext_vector_type(8)));
typedef _Float16 half4 __attribute__((ext_vector_type(4)));
typedef _Float16 half2_t __attribute__((ext_vector_type(2)));
typedef float floatx4 __attribute__((ext_vector_type(4)));

__device__ __forceinline__ floatx4 mfma16(half8 a, half8 b, floatx4 c) {
  return __builtin_amdgcn_mfma_f32_16x16x32_f16(a, b, c, 0, 0, 0);
}
__device__ __forceinline__ floatx4 mfma16k16(half4 a, half4 b, floatx4 c) {
  return __builtin_amdgcn_mfma_f32_16x16x16f16(a, b, c, 0, 0, 0);
}

__device__ __forceinline__ double fracd(double x) { return x - floor(x); }

// ---------------------------------------------------------------------------
// parallel boundary scan for one phase: n elements, increment c.
// ---------------------------------------------------------------------------
__device__ int scan_phase(int n, double c, int* __restrict__ ids,
                          int* __restrict__ startg, float* __restrict__ cntg,
                          int* __restrict__ wsum, int t)
{
  int loc[8];
  const int base = t * 8;
#pragma unroll
  for (int j = 0; j < 8; ++j) {
    const int i = base + j;
    int f = 0;
    if (i < n) {
      const int pidx = (i == 0) ? n : i;   // roll: prev of elem 0 is elem n-1
      f = (fracd((double)(i + 1) * c) < fracd((double)pidx * c)) ? 1 : 0;
    }
    loc[j] = f + ((j > 0) ? loc[j - 1] : 0);
  }
  wsum[t] = loc[7];
  __syncthreads();
  for (int off = 1; off < 256; off <<= 1) {
    int u = 0;
    if (t >= off) u = wsum[t - off];
    __syncthreads();
    wsum[t] += u;
    __syncthreads();
  }
  const int excl = wsum[t] - loc[7];
  const int m = wsum[255];
#pragma unroll
  for (int j = 0; j < 8; ++j) {
    const int i = base + j;
    if (i < n) {
      const int id = excl + loc[j];
      ids[i] = id;
      const int f = loc[j] - ((j > 0) ? loc[j - 1] : 0);
      if (f) startg[id - 1] = i;
    }
  }
  __syncthreads();
  for (int j = t; j < m; j += 256)
    cntg[j] = (float)((((j + 1) < m) ? startg[j + 1] : n) - startg[j]);
  __syncthreads();
  return m;
}

// ---------------------------------------------------------------------------
__global__ __launch_bounds__(256)
void meta_kernel(const float* __restrict__ mw, const float* __restrict__ mb,
                 const float* __restrict__ gw, const float* __restrict__ gb,
                 int* __restrict__ mi,
                 int* __restrict__ start1, float* __restrict__ cnt1,
                 int* __restrict__ start2, float* __restrict__ cnt2,
                 int* __restrict__ gmap)
{
  __shared__ int ids1[TT];
  __shared__ int ids2[TT];
  __shared__ int wsum[256];
  __shared__ double dsh[256];
  const int t = threadIdx.x;

  double s1 = 0.0, s2 = 0.0;
  for (int i = t; i < TD; i += 256) { s1 += (double)mw[i]; s2 += (double)gw[i]; }
  dsh[t] = s1; __syncthreads();
  for (int off = 128; off > 0; off >>= 1) {
    if (t < off) dsh[t] += dsh[t + off];
    __syncthreads();
  }
  const double c1 = dsh[0] + (double)mb[0];
  __syncthreads();
  dsh[t] = s2; __syncthreads();
  for (int off = 128; off > 0; off >>= 1) {
    if (t < off) dsh[t] += dsh[t + off];
    __syncthreads();
  }
  const double c2 = dsh[0] + (double)gb[0];
  __syncthreads();

  const int m1 = scan_phase(TT, c1, ids1, start1, cnt1, wsum, t);
  const int m2 = scan_phase(m1, c2, ids2, start2, cnt2, wsum, t);

  int i0 = TT;
  if (m1 >= 1 && m2 >= 1) i0 = start1[start2[0]];
  const int ntok = TT - i0;

  if (t == 0) {
    mi[MI_M1] = m1; mi[MI_M2] = m2; mi[MI_NTOK] = ntok;
    const int offcw = TB * ntok * TD;
    mi[MI_OFF_CW] = offcw;
    mi[MI_OFF_BW] = offcw + TB * TT * TT;
    mi[MI_OFF_GW] = offcw + TB * TT * TT + TB * m1 * m1;
    mi[MI_MCHAR] = TB * TT;
    mi[MI_MBLOCK] = TB * m1;
    mi[MI_MGLOB] = TB * m2;
    mi[MI_SEQC] = TT;
    mi[MI_SEQB] = m1;
    mi[MI_SEQG] = m2;
  }
  for (int i = i0 + t; i < TT; i += 256)
    gmap[i - i0] = ids2[ids1[i] - 1] - 1;
}

// ---------------------------------------------------------------------------
// GEMM 128m x 64n tile: C[M,N] = A[M,512] @ W[N,512]^T + bias.
// SPLIT=true: split-f16 3-product (fp32-grade).  SPLIT=false: plain f16
// (for outputs that are rounded to f16 anyway — qkv path).
// ---------------------------------------------------------------------------
template <typename OutT, bool SPLIT>
__global__ __launch_bounds__(256)
void gemm_mfma(const float* __restrict__ A, const float* __restrict__ W,
               const float* __restrict__ bias, OutT* __restrict__ C,
               const int* __restrict__ mi, int m_slot, int N)
{
  const int M = mi[m_slot];
  const int bm = blockIdx.y * 128;
  if (bm >= M) return;
  const int bn = blockIdx.x * 64;
  __shared__ _Float16 Ah[128][40];
  __shared__ _Float16 Wh[64][40];
  __shared__ _Float16 Al[SPLIT ? 128 : 1][40];
  __shared__ _Float16 Wl[SPLIT ? 64 : 1][40];

  const int t = threadIdx.x;
  const int wv = t >> 6;
  const int lane = t & 63;
  const int l15 = lane & 15;
  const int quad = lane >> 4;
  const int srowA = t >> 1;
  const int ssegA = (t & 1) * 16;
  const int srowW = t >> 2;
  const int ssegW = (t & 3) * 8;

  floatx4 acc[2][4];
#pragma unroll
  for (int i = 0; i < 2; ++i)
#pragma unroll
    for (int j = 0; j < 4; ++j) acc[i][j] = (floatx4){0.f, 0.f, 0.f, 0.f};

  for (int kk = 0; kk < TD; kk += 32) {
    __syncthreads();
    {
      const int ar = bm + srowA;
#pragma unroll
      for (int u = 0; u < 4; ++u) {
        float4 av = make_float4(0.f, 0.f, 0.f, 0.f);
        if (ar < M) av = *(const float4*)&A[(size_t)ar * TD + kk + ssegA + u * 4];
        const float aa[4] = {av.x, av.y, av.z, av.w};
        half4 hi, lo;
#pragma unroll
        for (int e = 0; e < 4; ++e) {
          const _Float16 h = (_Float16)aa[e];
          hi[e] = h;
          if constexpr (SPLIT) lo[e] = (_Float16)(aa[e] - (float)h);
        }
        *(half4*)&Ah[srowA][ssegA + u * 4] = hi;
        if constexpr (SPLIT) *(half4*)&Al[srowA][ssegA + u * 4] = lo;
      }
#pragma unroll
      for (int u = 0; u < 2; ++u) {
        const float4 wvv = *(const float4*)&W[(size_t)(bn + srowW) * TD + kk + ssegW + u * 4];
        const float ww[4] = {wvv.x, wvv.y, wvv.z, wvv.w};
        half4 hi, lo;
#pragma unroll
        for (int e = 0; e < 4; ++e) {
          const _Float16 h = (_Float16)ww[e];
          hi[e] = h;
          if constexpr (SPLIT) lo[e] = (_Float16)(ww[e] - (float)h);
        }
        *(half4*)&Wh[srowW][ssegW + u * 4] = hi;
        if constexpr (SPLIT) *(half4*)&Wl[srowW][ssegW + u * 4] = lo;
      }
    }
    __syncthreads();
    half8 ah[2], al[2];
#pragma unroll
    for (int mp = 0; mp < 2; ++mp) {
      ah[mp] = *(const half8*)&Ah[wv * 32 + mp * 16 + l15][quad * 8];
      if constexpr (SPLIT) al[mp] = *(const half8*)&Al[wv * 32 + mp * 16 + l15][quad * 8];
    }
#pragma unroll
    for (int np = 0; np < 4; ++np) {
      const half8 bh = *(const half8*)&Wh[np * 16 + l15][quad * 8];
      if constexpr (SPLIT) {
        const half8 bl = *(const half8*)&Wl[np * 16 + l15][quad * 8];
#pragma unroll
        for (int mp = 0; mp < 2; ++mp) {
          acc[mp][np] = mfma16(al[mp], bh, acc[mp][np]);
          acc[mp][np] = mfma16(ah[mp], bl, acc[mp][np]);
          acc[mp][np] = mfma16(ah[mp], bh, acc[mp][np]);
        }
      } else {
#pragma unroll
        for (int mp = 0; mp < 2; ++mp)
          acc[mp][np] = mfma16(ah[mp], bh, acc[mp][np]);
      }
    }
  }
  float bv[4];
#pragma unroll
  for (int np = 0; np < 4; ++np) bv[np] = bias[bn + np * 16 + l15];
#pragma unroll
  for (int mp = 0; mp < 2; ++mp) {
#pragma unroll
    for (int r = 0; r < 4; ++r) {
      const int row = bm + wv * 32 + mp * 16 + quad * 4 + r;
      if (row < M) {
        OutT* cp = &C[(size_t)row * N + bn];
#pragma unroll
        for (int np = 0; np < 4; ++np)
          cp[np * 16 + l15] = (OutT)(acc[mp][np][r] + bv[np]);
      }
    }
  }
}

// ---------------------------------------------------------------------------
// Proj GEMM with fused combine, 64m x 64n tile (grid 2 blocks/CU):
// A-row = (sum_z O_z f16) * 1/(sum_z l_z); A staged split hi/lo.
// ---------------------------------------------------------------------------
__global__ __launch_bounds__(256)
void gemm_norm_mfma(const _Float16* __restrict__ Ob, const float* __restrict__ lb,
                    const float* __restrict__ W, const float* __restrict__ bias,
                    float* __restrict__ C, const int* __restrict__ mi,
                    int m_slot, int seq_slot)
{
  const int M = mi[m_slot];
  const int bm = blockIdx.y * 64;
  if (bm >= M) return;
  const int seq = mi[seq_slot];
  const int bn = blockIdx.x * 64;
  __shared__ _Float16 Ah[64][40];
  __shared__ _Float16 Al[64][40];
  __shared__ _Float16 Wh[64][40];
  __shared__ _Float16 Wl[64][40];

  const int t = threadIdx.x;
  const int wv = t >> 6;
  const int lane = t & 63;
  const int l15 = lane & 15;
  const int quad = lane >> 4;
  const int srow = t >> 2;
  const int sseg = (t & 3) * 8;

  const int ar = bm + srow;
  const int ab = (ar >= seq) ? 1 : 0;
  const int aq = ar - ab * seq;

  floatx4 acc[4];
#pragma unroll
  for (int j = 0; j < 4; ++j) acc[j] = (floatx4){0.f, 0.f, 0.f, 0.f};

  for (int kk = 0; kk < TD; kk += 32) {
    __syncthreads();
    {
      float aa[8] = {0.f, 0.f, 0.f, 0.f, 0.f, 0.f, 0.f, 0.f};
      if (ar < M) {
        const size_t off = (size_t)ar * TD + kk + sseg;
#pragma unroll
        for (int z = 0; z < KC; ++z) {
          const half8 hv = *(const half8*)&Ob[(size_t)z * 2097152 + off];
#pragma unroll
          for (int e = 0; e < 8; ++e) aa[e] += (float)hv[e];
        }
        const int h = kk >> 6;
        const size_t lidx = ((size_t)(ab * TH + h)) * 2048 + aq;
        float lt = 0.f;
#pragma unroll
        for (int z = 0; z < KC; ++z) lt += lb[(size_t)z * 32768 + lidx];
        const float linv = 1.f / lt;
#pragma unroll
        for (int e = 0; e < 8; ++e) aa[e] *= linv;
      }
      half8 hi, lo;
#pragma unroll
      for (int e = 0; e < 8; ++e) {
        const _Float16 h = (_Float16)aa[e];
        hi[e] = h; lo[e] = (_Float16)(aa[e] - (float)h);
      }
      *(half8*)&Ah[srow][sseg] = hi;
      *(half8*)&Al[srow][sseg] = lo;

      const float4 w0 = *(const float4*)&W[(size_t)(bn + srow) * TD + kk + sseg];
      const float4 w1 = *(const float4*)&W[(size_t)(bn + srow) * TD + kk + sseg + 4];
      const float ww[8] = {w0.x, w0.y, w0.z, w0.w, w1.x, w1.y, w1.z, w1.w};
      half8 whi, wlo;
#pragma unroll
      for (int e = 0; e < 8; ++e) {
        const _Float16 h = (_Float16)ww[e];
        whi[e] = h; wlo[e] = (_Float16)(ww[e] - (float)h);
      }
      *(half8*)&Wh[srow][sseg] = whi;
      *(half8*)&Wl[srow][sseg] = wlo;
    }
    __syncthreads();
    const half8 ah = *(const half8*)&Ah[wv * 16 + l15][quad * 8];
    const half8 al = *(const half8*)&Al[wv * 16 + l15][quad * 8];
#pragma unroll
    for (int np = 0; np < 4; ++np) {
      const half8 bh = *(const half8*)&Wh[np * 16 + l15][quad * 8];
      const half8 bl = *(const half8*)&Wl[np * 16 + l15][quad * 8];
      acc[np] = mfma16(al, bh, acc[np]);
      acc[np] = mfma16(ah, bl, acc[np]);
      acc[np] = mfma16(ah, bh, acc[np]);
    }
  }
  float bv[4];
#pragma unroll
  for (int np = 0; np < 4; ++np) bv[np] = bias[bn + np * 16 + l15];
#pragma unroll
  for (int r = 0; r < 4; ++r) {
    const int row = bm + wv * 16 + quad * 4 + r;
    if (row < M) {
      float* cp = &C[(size_t)row * 512 + bn];
#pragma unroll
      for (int np = 0; np < 4; ++np)
        cp[np * 16 + l15] = acc[np][r] + bv[np];
    }
  }
}

// ---------------------------------------------------------------------------
// attn pass1, split-K x4 (z = chunk), S^T-trick.  q-tile 128, 4 waves x 32 q.
// Partials: O_z f16 (unnormalized), l_z f32.
// ---------------------------------------------------------------------------
__global__ __launch_bounds__(256)
void attn1_mfma(const _Float16* __restrict__ qkv,
                float* __restrict__ lbase, _Float16* __restrict__ Obase,
                const int* __restrict__ mi, int seq_slot)
{
  const int seq = mi[seq_slot];
  const int q0 = blockIdx.x * 128;
  if (q0 >= seq) return;
  const int b = blockIdx.y >> 3, h = blockIdx.y & 7;
  const int z = blockIdx.z;
  float* lP = lbase + (size_t)z * 32768;
  _Float16* oP = Obase + (size_t)z * 2097152;
  const int t = threadIdx.x;
  const int wv = t >> 6;
  const int lane = t & 63;
  const int l15 = lane & 15;
  const int quad = lane >> 4;

  __shared__ __align__(16) char smem_raw[18432];
  _Float16 (*Kf)[72] = (_Float16 (*)[72])smem_raw;              // 64x72 f16
  _Float16 (*Vt)[72] = (_Float16 (*)[72])(smem_raw + 9216);     // 64x72 f16
  float    (*Ot)[68] = (float (*)[68])smem_raw;                 // epilogue reuse

  half8 qB[2][2];
#pragma unroll
  for (int mp = 0; mp < 2; ++mp) {
    const int qrow = q0 + wv * 32 + mp * 16 + l15;
#pragma unroll
    for (int c = 0; c < 2; ++c) {
      half8 v = {};
      if (qrow < seq)
        v = *(const half8*)&qkv[((size_t)(b * seq + qrow)) * 1536 + h * 64 + c * 32 + quad * 8];
      qB[mp][c] = v;
    }
  }
  half4 onesA;
#pragma unroll
  for (int j = 0; j < 4; ++j) onesA[j] = (_Float16)1.0f;

  floatx4 oacc[2][4];
#pragma unroll
  for (int i = 0; i < 2; ++i)
#pragma unroll
    for (int j = 0; j < 4; ++j) oacc[i][j] = (floatx4){0.f, 0.f, 0.f, 0.f};
  floatx4 lacc[2] = {(floatx4){0.f, 0.f, 0.f, 0.f}, (floatx4){0.f, 0.f, 0.f, 0.f}};

  const int nkt = (seq + 63) >> 6;
  const int nkc = (nkt + KC - 1) / KC;
  const int kt_beg = z * nkc;
  const int kt_end = min(kt_beg + nkc, nkt);

  for (int kt = kt_beg; kt < kt_end; ++kt) {
    const int k0 = kt * 64;
    __syncthreads();
    {
      const int row = t >> 2;
      const int seg = (t & 3) * 16;
      const int kg = k0 + row;
      half8 v0 = {}, v1 = {};
      if (kg < seq) {
        const _Float16* base = &qkv[((size_t)(b * seq + kg)) * 1536 + 512 + h * 64 + seg];
        v0 = *(const half8*)base;
        v1 = *(const half8*)(base + 8);
      }
      *(half8*)&Kf[row][seg] = v0;
      *(half8*)&Kf[row][seg + 8] = v1;
    }
    {
      const int tp = lane & 31;
      const int dsel = lane >> 5;
      const int dbase = wv * 16 + dsel * 8;
      const int kg0 = k0 + tp * 2;
      half8 vA = {}, vB = {};
      if (kg0 < seq)
        vA = *(const half8*)&qkv[((size_t)(b * seq + kg0)) * 1536 + 1024 + h * 64 + dbase];
      if (kg0 + 1 < seq)
        vB = *(const half8*)&qkv[((size_t)(b * seq + kg0 + 1)) * 1536 + 1024 + h * 64 + dbase];
#pragma unroll
      for (int j = 0; j < 8; ++j) {
        half2_t pk; pk[0] = vA[j]; pk[1] = vB[j];
        *(half2_t*)&Vt[dbase + j][tp * 2] = pk;
      }
    }
    __syncthreads();

#pragma unroll
    for (int p = 0; p < 4; ++p) {
      floatx4 sT[2] = {(floatx4){0.f, 0.f, 0.f, 0.f}, (floatx4){0.f, 0.f, 0.f, 0.f}};
#pragma unroll
      for (int c = 0; c < 2; ++c) {
        const half8 kA = *(const half8*)&Kf[p * 16 + l15][c * 32 + quad * 8];
#pragma unroll
        for (int mp = 0; mp < 2; ++mp)
          sT[mp] = mfma16(kA, qB[mp][c], sT[mp]);
      }
      half4 vA[4];
#pragma unroll
      for (int dblk = 0; dblk < 4; ++dblk)
        vA[dblk] = *(const half4*)&Vt[dblk * 16 + l15][p * 16 + quad * 4];
      const int kg = k0 + p * 16 + quad * 4;
#pragma unroll
      for (int mp = 0; mp < 2; ++mp) {
        half4 eB;
#pragma unroll
        for (int r = 0; r < 4; ++r) {
          const float e = (kg + r < seq) ? __expf(sT[mp][r] * 0.125f) : 0.f;
          eB[r] = (_Float16)e;
        }
        lacc[mp] = mfma16k16(onesA, eB, lacc[mp]);
#pragma unroll
        for (int dblk = 0; dblk < 4; ++dblk)
          oacc[mp][dblk] = mfma16k16(vA[dblk], eB, oacc[mp][dblk]);
      }
    }
  }

  __syncthreads();   // K/V LDS done — reuse as Ot

#pragma unroll
  for (int mp = 0; mp < 2; ++mp) {
#pragma unroll
    for (int dblk = 0; dblk < 4; ++dblk)
      *(floatx4*)&Ot[wv * 16 + l15][dblk * 16 + quad * 4] = oacc[mp][dblk];
    const int ql = lane >> 2;
    const int dseg = (lane & 3) * 4;
    const int qg = q0 + wv * 32 + mp * 16 + ql;
    if (qg < seq) {
      _Float16* op = &oP[((size_t)(b * seq + qg)) * 512 + h * 64];
#pragma unroll
      for (int u = 0; u < 4; ++u) {
        const float4 v = *(const float4*)&Ot[wv * 16 + ql][u * 16 + dseg];
        half4 hv;
        hv[0] = (_Float16)v.x; hv[1] = (_Float16)v.y;
        hv[2] = (_Float16)v.z; hv[3] = (_Float16)v.w;
        *(half4*)(op + u * 16 + dseg) = hv;
      }
    }
    if (quad == 0) {
      const int qg2 = q0 + wv * 32 + mp * 16 + l15;
      if (qg2 < seq)
        lP[((size_t)(b * TH + h)) * 2048 + qg2] = lacc[mp][0];
    }
  }
}

// ---------------------------------------------------------------------------
// attn pass2 (plain f16 MFMA), q-tile 64 x k-tile 128; Linv = 1/(sum_z l_z).
// ---------------------------------------------------------------------------
__global__ __launch_bounds__(256)
void attn2_mfma(const _Float16* __restrict__ qkv,
                const float* __restrict__ lb,
                float* __restrict__ outb, const int* __restrict__ mi,
                int seq_slot, int off_slot)
{
  const int seq = mi[seq_slot];
  const int q0 = blockIdx.y * 64;
  const int k0 = blockIdx.x * 128;
  if (q0 >= seq || k0 >= seq) return;
  const int b = blockIdx.z;
  const int woff = mi[off_slot];
  float* wout = outb + (size_t)woff + (size_t)b * seq * seq;

  __shared__ _Float16 Qs[64][72];
  __shared__ _Float16 Ksh[128][72];
  __shared__ float Linv[64];

  const int t = threadIdx.x;
  const int wv = t >> 6;
  const int lane = t & 63;
  const int l15 = lane & 15;
  const int quad = lane >> 4;
  const int srowQ = t >> 2;
  const int ssegQ = (t & 3) * 16;
  const int srowK = t >> 1;
  const int ssegK = (t & 1) * 32;

  floatx4 acc[8];
#pragma unroll
  for (int j = 0; j < 8; ++j) acc[j] = (floatx4){0.f, 0.f, 0.f, 0.f};

  for (int h = 0; h < TH; ++h) {
    __syncthreads();
    {
      const int qr = q0 + srowQ;
      half8 q0v = {}, q1v = {};
      if (qr < seq) {
        const _Float16* base = &qkv[((size_t)(b * seq + qr)) * 1536 + h * 64 + ssegQ];
        q0v = *(const half8*)base;
        q1v = *(const half8*)(base + 8);
      }
      *(half8*)&Qs[srowQ][ssegQ] = q0v;
      *(half8*)&Qs[srowQ][ssegQ + 8] = q1v;

      const int kr = k0 + srowK;
#pragma unroll
      for (int u = 0; u < 4; ++u) {
        half8 kv = {};
        if (kr < seq)
          kv = *(const half8*)&qkv[((size_t)(b * seq + kr)) * 1536 + 512 + h * 64 + ssegK + u * 8];
        *(half8*)&Ksh[srowK][ssegK + u * 8] = kv;
      }
      if (t < 64) {
        float lv = 1.f;
        if (q0 + t < seq) {
          const size_t lidx = ((size_t)(b * TH + h)) * 2048 + q0 + t;
          float lt = 0.f;
#pragma unroll
          for (int z = 0; z < KC; ++z) lt += lb[(size_t)z * 32768 + lidx];
          lv = lt;
        }
        Linv[t] = 1.f / lv;
      }
    }
    __syncthreads();

    half8 af[2];
#pragma unroll
    for (int c = 0; c < 2; ++c)
      af[c] = *(const half8*)&Qs[wv * 16 + l15][c * 32 + quad * 8];
    float lv[4];
#pragma unroll
    for (int r = 0; r < 4; ++r)
      lv[r] = Linv[wv * 16 + quad * 4 + r];

#pragma unroll
    for (int np = 0; np < 8; ++np) {
      half8 bf[2];
#pragma unroll
      for (int c = 0; c < 2; ++c)
        bf[c] = *(const half8*)&Ksh[np * 16 + l15][c * 32 + quad * 8];
      floatx4 s = (floatx4){0.f, 0.f, 0.f, 0.f};
      s = mfma16(af[0], bf[0], s);
      s = mfma16(af[1], bf[1], s);
#pragma unroll
      for (int r = 0; r < 4; ++r)
        acc[np][r] += __expf(s[r] * 0.125f) * lv[r];
    }
  }

#pragma unroll
  for (int r = 0; r < 4; ++r) {
    const int qg = q0 + wv * 16 + quad * 4 + r;
    if (qg >= seq) continue;
    float* rowp = wout + (size_t)qg * seq;
#pragma unroll
    for (int np = 0; np < 8; ++np) {
      const int col = k0 + np * 16 + l15;
      if (col < seq) rowp[col] = acc[np][r] * 0.125f;
    }
  }
}

// ---------------------------------------------------------------------------
__global__ __launch_bounds__(256)
void merge_kernel(const float* __restrict__ src, float* __restrict__ dst,
                  const int* __restrict__ start, const float* __restrict__ cnt,
                  const int* __restrict__ mi, int seqin_slot, int seqout_slot)
{
  const int j = blockIdx.x;
  const int b = blockIdx.y;
  const int seqo = mi[seqout_slot];
  if (j >= seqo) return;
  const int seqi = mi[seqin_slot];
  const int s = start[j];
  const float cf = cnt[j];
  const int n = (int)cf;
  const int d0 = threadIdx.x * 2;
  float s0 = 0.f, s1 = 0.f;
  const float* p = &src[((size_t)b * seqi + s) * TD + d0];
  for (int i = 0; i < n; ++i) {
    const float2 v = *(const float2*)p;
    s0 += v.x; s1 += v.y;
    p += TD;
  }
  const float inv = 1.f / (cf + 1e-10f);
  float2 o; o.x = s0 * inv; o.y = s1 * inv;
  *(float2*)&dst[((size_t)b * seqo + j) * TD + d0] = o;
}

__global__ __launch_bounds__(256)
void expand_kernel(const float* __restrict__ gout, float* __restrict__ dout,
                   const int* __restrict__ gmap, const int* __restrict__ mi)
{
  const int j = blockIdx.x;
  const int b = blockIdx.y;
  const int ntok = mi[MI_NTOK];
  if (j >= ntok) return;
  const int m2 = mi[MI_M2];
  const int g = gmap[j];
  const int d0 = threadIdx.x * 2;
  const float2 v = *(const float2*)&gout[((size_t)b * m2 + g) * TD + d0];
  *(float2*)&dout[((size_t)b * ntok + j) * TD + d0] = v;
}

// ---------------------------------------------------------------------------
extern "C" void kernel_launch(void* const* d_in, const int* in_sizes, int n_in,
                              void* d_out, int out_size, void* d_ws, size_t ws_size,
                              hipStream_t stream)
{
  const float* x   = (const float*)d_in[0];
  const float* cWi = (const float*)d_in[1];
  const float* cbi = (const float*)d_in[2];
  const float* cWo = (const float*)d_in[3];
  const float* cbo = (const float*)d_in[4];
  const float* bWi = (const float*)d_in[5];
  const float* bbi = (const float*)d_in[6];
  const float* bWo = (const float*)d_in[7];
  const float* bbo = (const float*)d_in[8];
  const float* gWi = (const float*)d_in[9];
  const float* gbi = (const float*)d_in[10];
  const float* gWo = (const float*)d_in[11];
  const float* gbo = (const float*)d_in[12];
  const float* mw  = (const float*)d_in[13];
  const float* mbv = (const float*)d_in[14];
  const float* gw  = (const float*)d_in[15];
  const float* gbv = (const float*)d_in[16];
  float* outf = (float*)d_out;

  char* wsb = (char*)d_ws;
  int*   mi     = (int*)(wsb);
  int*   start1 = (int*)(wsb + 1024);
  float* cnt1   = (float*)(wsb + 1024 + 8192);
  int*   start2 = (int*)(wsb + 1024 + 2 * 8192);
  float* cnt2   = (float*)(wsb + 1024 + 3 * 8192);
  int*   gmap   = (int*)(wsb + 1024 + 4 * 8192);
  float* lbase  = (float*)(wsb + 65536);               // KC x 32768 f32 (512 KB)
  _Float16* qkv = (_Float16*)(wsb + 655360);           // 4096x1536 f16 (12.6 MB)
  _Float16* Obase = (_Float16*)(wsb + 655360 + 12582912);   // KC x 4 MB f16
  float* stg_o  = (float*)(wsb + 655360 + 12582912 + (size_t)KC * 4194304);  // 8 MB
  float* stg_m  = stg_o + 2097152;                     // 8 MB  (total ~46.8 MB)

  const dim3 blk(256);

  meta_kernel<<<dim3(1), blk, 0, stream>>>(mw, mbv, gw, gbv, mi, start1, cnt1, start2, cnt2, gmap);

  // ---- char stage ----
  gemm_mfma<_Float16, false><<<dim3(24, 32), blk, 0, stream>>>(x, cWi, cbi, qkv, mi, MI_MCHAR, 1536);
  attn1_mfma<<<dim3(16, 16, KC), blk, 0, stream>>>(qkv, lbase, Obase, mi, MI_SEQC);
  attn2_mfma<<<dim3(16, 32, 2), blk, 0, stream>>>(qkv, lbase, outf, mi, MI_SEQC, MI_OFF_CW);
  gemm_norm_mfma<<<dim3(8, 64), blk, 0, stream>>>(Obase, lbase, cWo, cbo, stg_o, mi, MI_MCHAR, MI_SEQC);
  merge_kernel<<<dim3(2048, 2), blk, 0, stream>>>(stg_o, stg_m, start1, cnt1, mi, MI_SEQC, MI_SEQB);

  // ---- block stage ----
  gemm_mfma<_Float16, false><<<dim3(24, 32), blk, 0, stream>>>(stg_m, bWi, bbi, qkv, mi, MI_MBLOCK, 1536);
  attn1_mfma<<<dim3(16, 16, KC), blk, 0, stream>>>(qkv, lbase, Obase, mi, MI_SEQB);
  attn2_mfma<<<dim3(16, 32, 2), blk, 0, stream>>>(qkv, lbase, outf, mi, MI_SEQB, MI_OFF_BW);
  gemm_norm_mfma<<<dim3(8, 64), blk, 0, stream>>>(Obase, lbase, bWo, bbo, stg_o, mi, MI_MBLOCK, MI_SEQB);
  merge_kernel<<<dim3(2048, 2), blk, 0, stream>>>(stg_o, stg_m, start2, cnt2, mi, MI_SEQB, MI_SEQG);

  // ---- glob stage ----
  gemm_mfma<_Float16, false><<<dim3(24, 32), blk, 0, stream>>>(stg_m, gWi, gbi, qkv, mi, MI_MGLOB, 1536);
  attn1_mfma<<<dim3(16, 16, KC), blk, 0, stream>>>(qkv, lbase, Obase, mi, MI_SEQG);
  attn2_mfma<<<dim3(16, 32, 2), blk, 0, stream>>>(qkv, lbase, outf, mi, MI_SEQG, MI_OFF_GW);
  gemm_norm_mfma<<<dim3(8, 64), blk, 0, stream>>>(Obase, lbase, gWo, gbo, stg_o, mi, MI_MGLOB, MI_SEQG);
  expand_kernel<<<dim3(2048, 2), blk, 0, stream>>>(stg_o, outf, gmap, mi);

  (void)in_sizes; (void)n_in; (void)out_size; (void)ws_size;
}